// Round 1
// baseline (338.183 us; speedup 1.0000x reference)
//
#include <hip/hip_runtime.h>
#include <math.h>

// Problem constants (from reference)
#define N_OUT_NODES 8192
#define C_OUT 32
#define NCELL 64            // 4*4*4
#define GDIM  192           // NCELL * C_IN
constexpr float INV_RADIUS   = 1.0f / 0.1125f;   // RADIUS = 1.5*6*0.025/2
constexpr float EPS          = 1e-12f;
constexpr float FOUR_OVER_PI = 1.27323954473516f;

__device__ __forceinline__ float sgnf(float v) {
    return (v > 0.f) ? 1.f : ((v < 0.f) ? -1.f : 0.f);
}

// Phase 1: per-edge scatter of trilinear density into G[n][cell][c]
__global__ __launch_bounds__(256) void edge_kernel(
    const float* __restrict__ vel,
    const float* __restrict__ pos0,
    const float* __restrict__ pos1,
    const int*   __restrict__ src,
    const int*   __restrict__ dst,
    const float* __restrict__ mask,
    float* __restrict__ G,
    int E)
{
    int e = blockIdx.x * blockDim.x + threadIdx.x;
    if (e >= E) return;
    float m = mask[e];
    if (m == 0.f) return;                     // skip padding (critical: dst=0 contention)
    int s = src[e];
    int d = dst[e];

    float rx = (pos0[3*s+0] - pos1[3*d+0]) * INV_RADIUS;
    float ry = (pos0[3*s+1] - pos1[3*d+1]) * INV_RADIUS;
    float rz = (pos0[3*s+2] - pos1[3*d+2]) * INV_RADIUS;
    float r2 = rx*rx + ry*ry + rz*rz;
    if (r2 >= 1.f) return;                    // window = 0
    float om  = 1.f - r2;
    float win = om*om*om * m;                 // (1-r2)^3 in (0,1], clip is a no-op

    // ball -> cube (volume preserving, Open3D mapping)
    float x = rx, y = ry, z = rz;
    float sq = r2;
    float norm = sqrtf(sq + EPS);
    float cx, cy, cz;
    if (sq < 1e-12f) {
        cx = 0.f; cy = 0.f; cz = 0.f;
    } else if (1.25f*z*z > x*x + y*y) {       // top/bottom cone
        float s_top = sqrtf(3.f*norm / (norm + fabsf(z) + EPS));
        cx = x * s_top;
        cy = y * s_top;
        cz = sgnf(z) * norm;
    } else {                                  // side
        float s_side = norm * rsqrtf(x*x + y*y + EPS);
        cx = x * s_side;
        cy = y * s_side;
        cz = 1.5f * z;
    }

    float nxy = sqrtf(cx*cx + cy*cy + EPS);
    float ux, uy;
    if (cx*cx >= cy*cy) {
        float xs = (fabsf(cx) > EPS) ? cx : 1.f;
        float sc = sgnf(cx);
        ux = sc * nxy;
        uy = sc * nxy * FOUR_OVER_PI * atanf(cy / xs);
    } else {
        float ys = (fabsf(cy) > EPS) ? cy : 1.f;
        float sc = sgnf(cy);
        ux = sc * nxy * FOUR_OVER_PI * atanf(cx / ys);
        uy = sc * nxy;
    }
    if (cx*cx + cy*cy < 1e-12f) { ux = 0.f; uy = 0.f; }

    // grid coords in [0,3], corner index + fractions
    float gx = fminf(fmaxf((ux + 1.f) * 1.5f, 0.f), 3.f);
    float gy = fminf(fmaxf((uy + 1.f) * 1.5f, 0.f), 3.f);
    float gz = fminf(fmaxf((cz + 1.f) * 1.5f, 0.f), 3.f);
    int ix = min((int)floorf(gx), 2);
    int iy = min((int)floorf(gy), 2);
    int iz = min((int)floorf(gz), 2);
    float fx = gx - (float)ix;
    float fy = gy - (float)iy;
    float fz = gz - (float)iz;

    float vx = vel[3*s+0], vy = vel[3*s+1], vz = vel[3*s+2];

    float wxs[2] = {1.f - fx, fx};
    float wys[2] = {1.f - fy, fy};
    float wzs[2] = {1.f - fz, fz};

    float* Gd = G + (size_t)d * GDIM;
    #pragma unroll
    for (int dz = 0; dz < 2; ++dz) {
        #pragma unroll
        for (int dy = 0; dy < 2; ++dy) {
            #pragma unroll
            for (int dx = 0; dx < 2; ++dx) {
                float w = wzs[dz] * wys[dy] * wxs[dx] * win;
                int idx = ((iz + dz) * 4 + (iy + dy)) * 4 + (ix + dx);
                atomicAdd(Gd + idx*3 + 0, w * vx);
                atomicAdd(Gd + idx*3 + 1, w * vy);
                atomicAdd(Gd + idx*3 + 2, w * vz);
            }
        }
    }
}

// Phase 2: out[n][o] = b[o] + sum_j G[n][j] * W[j][o]   (W already (64,3,32) row-major)
__global__ __launch_bounds__(256) void gemm_kernel(
    const float* __restrict__ G,
    const float* __restrict__ W,
    const float* __restrict__ b,
    float* __restrict__ out)
{
    __shared__ float Wl[GDIM * C_OUT];
    for (int i = threadIdx.x; i < GDIM * C_OUT; i += 256) Wl[i] = W[i];
    __syncthreads();

    int n = blockIdx.x * 8 + (threadIdx.x >> 5);
    int o = threadIdx.x & 31;
    const float* g = G + (size_t)n * GDIM;
    float acc = b[o];
    #pragma unroll 8
    for (int j = 0; j < GDIM; ++j) {
        acc += g[j] * Wl[j * C_OUT + o];
    }
    out[n * C_OUT + o] = acc;
}

extern "C" void kernel_launch(void* const* d_in, const int* in_sizes, int n_in,
                              void* d_out, int out_size, void* d_ws, size_t ws_size,
                              hipStream_t stream)
{
    const float* vel  = (const float*)d_in[0];
    const float* pos0 = (const float*)d_in[1];
    const float* pos1 = (const float*)d_in[2];
    const float* W    = (const float*)d_in[3];
    const float* b    = (const float*)d_in[4];
    const int*   src  = (const int*)d_in[5];
    const int*   dst  = (const int*)d_in[6];
    const float* mask = (const float*)d_in[7];
    int E = in_sizes[5];

    float* G = (float*)d_ws;   // 8192 * 192 * 4 = 6.29 MB
    hipMemsetAsync(G, 0, (size_t)N_OUT_NODES * GDIM * sizeof(float), stream);

    edge_kernel<<<(E + 255) / 256, 256, 0, stream>>>(vel, pos0, pos1, src, dst, mask, G, E);

    gemm_kernel<<<N_OUT_NODES / 8, 256, 0, stream>>>(G, W, b, (float*)d_out);
}

// Round 2
// 75.980 us; speedup vs baseline: 4.4509x; 4.4509x over previous
//
#include <hip/hip_runtime.h>
#include <math.h>

// Problem constants (from reference)
#define N_OUT_NODES 8192
#define C_OUT 32
#define NCELL 64            // 4*4*4
#define GDIM  192           // NCELL * C_IN
#define NODES_PER_BLOCK 4
constexpr float INV_RADIUS   = 1.0f / 0.1125f;   // RADIUS = 1.5*6*0.025/2
constexpr float EPS          = 1e-12f;
constexpr float FOUR_OVER_PI = 1.27323954473516f;

__device__ __forceinline__ float sgnf(float v) {
    return (v > 0.f) ? 1.f : ((v < 0.f) ? -1.f : 0.f);
}

// Kernel 1: CSR row offsets from the (sorted) dst array.
// mask is 1...1 0...0 -> binary search gives the real edge count.
__global__ __launch_bounds__(256) void offsets_kernel(
    const int* __restrict__ dst,
    const float* __restrict__ mask,
    int E,
    int* __restrict__ row_off)
{
    int n = blockIdx.x * blockDim.x + threadIdx.x;
    if (n > N_OUT_NODES) return;
    // E_real = first index where mask == 0
    int lo = 0, hi = E;
    while (lo < hi) { int mid = (lo + hi) >> 1; if (mask[mid] != 0.f) lo = mid + 1; else hi = mid; }
    int Ereal = lo;
    if (n == N_OUT_NODES) { row_off[n] = Ereal; return; }
    // lower_bound(dst[0:Ereal], n)
    lo = 0; hi = Ereal;
    while (lo < hi) { int mid = (lo + hi) >> 1; if (dst[mid] < n) lo = mid + 1; else hi = mid; }
    row_off[n] = lo;
}

// Kernel 2: fused edge-scatter (LDS) + per-node GEMV.
// One wave per destination node; 4 nodes per 256-thread block.
__global__ __launch_bounds__(256) void fused_kernel(
    const float* __restrict__ vel,
    const float* __restrict__ pos0,
    const float* __restrict__ pos1,
    const float* __restrict__ W,     // (192, 32) row-major
    const float* __restrict__ b,
    const int*   __restrict__ src,
    const int*   __restrict__ row_off,
    float* __restrict__ out)
{
    __shared__ float Wl[GDIM * C_OUT];              // 24 KiB
    __shared__ float Gl[NODES_PER_BLOCK][GDIM];     // 3 KiB
    __shared__ float bl[C_OUT];

    int t = threadIdx.x;
    for (int i = t; i < GDIM * C_OUT; i += 256) Wl[i] = W[i];
    if (t < C_OUT) bl[t] = b[t];
    for (int i = t; i < NODES_PER_BLOCK * GDIM; i += 256) ((float*)Gl)[i] = 0.f;
    __syncthreads();

    int wave = t >> 6, lane = t & 63;
    int n = blockIdx.x * NODES_PER_BLOCK + wave;
    float px = pos1[3*n+0], py = pos1[3*n+1], pz = pos1[3*n+2];
    int e0 = row_off[n], e1 = row_off[n+1];
    float* Gd = Gl[wave];

    for (int e = e0 + lane; e < e1; e += 64) {
        int s = src[e];
        float rx = (pos0[3*s+0] - px) * INV_RADIUS;
        float ry = (pos0[3*s+1] - py) * INV_RADIUS;
        float rz = (pos0[3*s+2] - pz) * INV_RADIUS;
        float r2 = rx*rx + ry*ry + rz*rz;
        if (r2 >= 1.f) continue;                    // window = 0
        float om  = 1.f - r2;
        float win = om*om*om;                       // mask==1 for all real edges

        // ball -> cube (volume preserving)
        float x = rx, y = ry, z = rz;
        float sq = r2;
        float norm = sqrtf(sq + EPS);
        float cx, cy, cz;
        if (sq < 1e-12f) {
            cx = 0.f; cy = 0.f; cz = 0.f;
        } else if (1.25f*z*z > x*x + y*y) {         // top/bottom cone
            float s_top = sqrtf(3.f*norm / (norm + fabsf(z) + EPS));
            cx = x * s_top;
            cy = y * s_top;
            cz = sgnf(z) * norm;
        } else {                                    // side
            float s_side = norm * rsqrtf(x*x + y*y + EPS);
            cx = x * s_side;
            cy = y * s_side;
            cz = 1.5f * z;
        }

        float nxy = sqrtf(cx*cx + cy*cy + EPS);
        float ux, uy;
        if (cx*cx >= cy*cy) {
            float xs = (fabsf(cx) > EPS) ? cx : 1.f;
            float sc = sgnf(cx);
            ux = sc * nxy;
            uy = sc * nxy * FOUR_OVER_PI * atanf(cy / xs);
        } else {
            float ys = (fabsf(cy) > EPS) ? cy : 1.f;
            float sc = sgnf(cy);
            ux = sc * nxy * FOUR_OVER_PI * atanf(cx / ys);
            uy = sc * nxy;
        }
        if (cx*cx + cy*cy < 1e-12f) { ux = 0.f; uy = 0.f; }

        // grid coords in [0,3], corner index + fractions
        float gx = fminf(fmaxf((ux + 1.f) * 1.5f, 0.f), 3.f);
        float gy = fminf(fmaxf((uy + 1.f) * 1.5f, 0.f), 3.f);
        float gz = fminf(fmaxf((cz + 1.f) * 1.5f, 0.f), 3.f);
        int ix = min((int)floorf(gx), 2);
        int iy = min((int)floorf(gy), 2);
        int iz = min((int)floorf(gz), 2);
        float fx = gx - (float)ix;
        float fy = gy - (float)iy;
        float fz = gz - (float)iz;

        float vx = vel[3*s+0], vy = vel[3*s+1], vz = vel[3*s+2];

        float wxs[2] = {1.f - fx, fx};
        float wys[2] = {1.f - fy, fy};
        float wzs[2] = {1.f - fz, fz};

        #pragma unroll
        for (int dz = 0; dz < 2; ++dz) {
            #pragma unroll
            for (int dy = 0; dy < 2; ++dy) {
                #pragma unroll
                for (int dx = 0; dx < 2; ++dx) {
                    float w = wzs[dz] * wys[dy] * wxs[dx] * win;
                    int idx = ((iz + dz) * 4 + (iy + dy)) * 4 + (ix + dx);
                    atomicAdd(&Gd[idx*3 + 0], w * vx);
                    atomicAdd(&Gd[idx*3 + 1], w * vy);
                    atomicAdd(&Gd[idx*3 + 2], w * vz);
                }
            }
        }
    }
    __syncthreads();

    // Per-node GEMV: 4 nodes x 32 outputs = 128 threads active
    if (t < NODES_PER_BLOCK * C_OUT) {
        int node = t >> 5, o = t & 31;
        const float* g = Gl[node];
        float acc = bl[o];
        #pragma unroll 8
        for (int j = 0; j < GDIM; ++j) {
            acc += g[j] * Wl[j * C_OUT + o];
        }
        out[(blockIdx.x * NODES_PER_BLOCK + node) * C_OUT + o] = acc;
    }
}

extern "C" void kernel_launch(void* const* d_in, const int* in_sizes, int n_in,
                              void* d_out, int out_size, void* d_ws, size_t ws_size,
                              hipStream_t stream)
{
    const float* vel  = (const float*)d_in[0];
    const float* pos0 = (const float*)d_in[1];
    const float* pos1 = (const float*)d_in[2];
    const float* W    = (const float*)d_in[3];
    const float* b    = (const float*)d_in[4];
    const int*   src  = (const int*)d_in[5];
    const int*   dst  = (const int*)d_in[6];
    const float* mask = (const float*)d_in[7];
    int E = in_sizes[5];

    int* row_off = (int*)d_ws;   // 8193 ints

    offsets_kernel<<<(N_OUT_NODES + 256) / 256, 256, 0, stream>>>(dst, mask, E, row_off);
    fused_kernel<<<N_OUT_NODES / NODES_PER_BLOCK, 256, 0, stream>>>(
        vel, pos0, pos1, W, b, src, row_off, (float*)d_out);
}

// Round 3
// 69.253 us; speedup vs baseline: 4.8833x; 1.0971x over previous
//
#include <hip/hip_runtime.h>
#include <math.h>

// Problem constants (from reference)
#define N_NODES 8192        // N_IN == N_OUT == 8192
#define C_OUT 32
#define GDIM  192           // 64 cells * 3 input channels
constexpr float INV_RADIUS   = 1.0f / 0.1125f;   // RADIUS = 1.5*6*0.025/2
constexpr float EPS          = 1e-12f;
constexpr float FOUR_OVER_PI = 1.27323954473516f;

__device__ __forceinline__ float sgnf(float v) {
    return (v > 0.f) ? 1.f : ((v < 0.f) ? -1.f : 0.f);
}

// Workspace layout (d_ws):
//   pv      : 8192 * 8 floats  (pos.xyz,0, vel.xyz,0)   = 262144 B  @ 0
//   row_off : 8193 ints                                  =  32772 B  @ 262144
//   G       : 8192 * 192 floats                          = 6291456 B @ 294928 (16B aligned)
#define PV_OFF   0
#define ROFF_OFF 262144
#define G_OFF    294928

// Kernel 1: CSR row offsets from sorted dst + pack pos0/vel into float4 pairs.
__global__ __launch_bounds__(256) void prep_kernel(
    const float* __restrict__ pos0,
    const float* __restrict__ vel,
    const int*   __restrict__ dst,
    const float* __restrict__ mask,
    int E,
    int*   __restrict__ row_off,
    float* __restrict__ pv)
{
    int n = blockIdx.x * blockDim.x + threadIdx.x;
    if (n < N_NODES) {
        float4 p = make_float4(pos0[3*n+0], pos0[3*n+1], pos0[3*n+2], 0.f);
        float4 v = make_float4(vel [3*n+0], vel [3*n+1], vel [3*n+2], 0.f);
        ((float4*)pv)[2*n+0] = p;
        ((float4*)pv)[2*n+1] = v;
    }
    if (n > N_NODES) return;
    // E_real = first index where mask == 0
    int lo = 0, hi = E;
    while (lo < hi) { int mid = (lo + hi) >> 1; if (mask[mid] != 0.f) lo = mid + 1; else hi = mid; }
    int Ereal = lo;
    if (n == N_NODES) { row_off[n] = Ereal; return; }
    // lower_bound(dst[0:Ereal], n)
    lo = 0; hi = Ereal;
    while (lo < hi) { int mid = (lo + hi) >> 1; if (dst[mid] < n) lo = mid + 1; else hi = mid; }
    row_off[n] = lo;
}

// Kernel 2: one wave per destination node; accumulate density row in LDS
// (wave-private -> NO barriers), then one coalesced row store to G.
__global__ __launch_bounds__(256) void scatter_kernel(
    const float* __restrict__ pv,
    const float* __restrict__ pos1,
    const int*   __restrict__ src,
    const int*   __restrict__ row_off,
    float* __restrict__ G)
{
    __shared__ float Gl[4][GDIM];                   // 3 KiB only
    int t = threadIdx.x, wave = t >> 6, lane = t & 63;
    int n = blockIdx.x * 4 + wave;
    float* Gd = Gl[wave];

    // zero own row (wave-private, LDS is in-order per wave: no barrier)
    #pragma unroll
    for (int i = lane; i < GDIM; i += 64) Gd[i] = 0.f;

    float px = pos1[3*n+0], py = pos1[3*n+1], pz = pos1[3*n+2];
    int e0 = row_off[n], e1 = row_off[n+1];

    for (int e = e0 + lane; e < e1; e += 64) {
        int s = src[e];
        float4 p = ((const float4*)pv)[2*s+0];
        float4 v = ((const float4*)pv)[2*s+1];
        float rx = (p.x - px) * INV_RADIUS;
        float ry = (p.y - py) * INV_RADIUS;
        float rz = (p.z - pz) * INV_RADIUS;
        float r2 = rx*rx + ry*ry + rz*rz;
        if (r2 >= 1.f) continue;
        float om  = 1.f - r2;
        float win = om*om*om;                       // mask==1 for all real edges

        // ball -> cube (volume preserving)
        float x = rx, y = ry, z = rz;
        float norm = sqrtf(r2 + EPS);
        float cx, cy, cz;
        if (r2 < 1e-12f) {
            cx = 0.f; cy = 0.f; cz = 0.f;
        } else if (1.25f*z*z > x*x + y*y) {         // top/bottom cone
            float s_top = sqrtf(3.f*norm / (norm + fabsf(z) + EPS));
            cx = x * s_top;
            cy = y * s_top;
            cz = sgnf(z) * norm;
        } else {                                    // side
            float s_side = norm * rsqrtf(x*x + y*y + EPS);
            cx = x * s_side;
            cy = y * s_side;
            cz = 1.5f * z;
        }

        float nxy = sqrtf(cx*cx + cy*cy + EPS);
        float ux, uy;
        if (cx*cx >= cy*cy) {
            float xs = (fabsf(cx) > EPS) ? cx : 1.f;
            float sc = sgnf(cx);
            ux = sc * nxy;
            uy = sc * nxy * FOUR_OVER_PI * atanf(cy / xs);
        } else {
            float ys = (fabsf(cy) > EPS) ? cy : 1.f;
            float sc = sgnf(cy);
            ux = sc * nxy * FOUR_OVER_PI * atanf(cx / ys);
            uy = sc * nxy;
        }
        if (cx*cx + cy*cy < 1e-12f) { ux = 0.f; uy = 0.f; }

        // grid coords in [0,3], corner index + fractions
        float gx = fminf(fmaxf((ux + 1.f) * 1.5f, 0.f), 3.f);
        float gy = fminf(fmaxf((uy + 1.f) * 1.5f, 0.f), 3.f);
        float gz = fminf(fmaxf((cz + 1.f) * 1.5f, 0.f), 3.f);
        int ix = min((int)floorf(gx), 2);
        int iy = min((int)floorf(gy), 2);
        int iz = min((int)floorf(gz), 2);
        float fx = gx - (float)ix;
        float fy = gy - (float)iy;
        float fz = gz - (float)iz;

        float wxs[2] = {1.f - fx, fx};
        float wys[2] = {1.f - fy, fy};
        float wzs[2] = {1.f - fz, fz};

        #pragma unroll
        for (int dz = 0; dz < 2; ++dz)
            #pragma unroll
            for (int dy = 0; dy < 2; ++dy)
                #pragma unroll
                for (int dx = 0; dx < 2; ++dx) {
                    float w = wzs[dz] * wys[dy] * wxs[dx] * win;
                    int idx = ((iz + dz) * 4 + (iy + dy)) * 4 + (ix + dx);
                    atomicAdd(&Gd[idx*3 + 0], w * v.x);
                    atomicAdd(&Gd[idx*3 + 1], w * v.y);
                    atomicAdd(&Gd[idx*3 + 2], w * v.z);
                }
    }

    // same-wave DS ordering guarantees atomics are visible; coalesced row store
    if (lane < GDIM/4) {
        float4 r = ((float4*)Gd)[lane];
        ((float4*)(G + (size_t)n * GDIM))[lane] = r;
    }
}

// Kernel 3: out[n][o] = b[o] + sum_j G[n][j] * W[j][o]; 8 nodes per 256-thr block.
__global__ __launch_bounds__(256) void gemm_kernel(
    const float* __restrict__ G,
    const float* __restrict__ W,
    const float* __restrict__ b,
    float* __restrict__ out)
{
    __shared__ float Wl[GDIM * C_OUT];   // 24 KiB
    __shared__ float Gls[8 * GDIM];      //  6 KiB
    __shared__ float bl[C_OUT];
    int t = threadIdx.x;
    for (int i = t; i < GDIM * C_OUT / 4; i += 256)
        ((float4*)Wl)[i] = ((const float4*)W)[i];
    if (t < C_OUT) bl[t] = b[t];
    const float4* Gg = (const float4*)(G + (size_t)blockIdx.x * 8 * GDIM);
    for (int i = t; i < 8 * GDIM / 4; i += 256)
        ((float4*)Gls)[i] = Gg[i];
    __syncthreads();

    int node = t >> 5, o = t & 31;
    const float* g = Gls + node * GDIM;
    float acc = bl[o];
    #pragma unroll 8
    for (int j = 0; j < GDIM; ++j)
        acc += g[j] * Wl[j * C_OUT + o];
    out[(blockIdx.x * 8 + node) * C_OUT + o] = acc;
}

extern "C" void kernel_launch(void* const* d_in, const int* in_sizes, int n_in,
                              void* d_out, int out_size, void* d_ws, size_t ws_size,
                              hipStream_t stream)
{
    const float* vel  = (const float*)d_in[0];
    const float* pos0 = (const float*)d_in[1];
    const float* pos1 = (const float*)d_in[2];
    const float* W    = (const float*)d_in[3];
    const float* b    = (const float*)d_in[4];
    const int*   src  = (const int*)d_in[5];
    const int*   dst  = (const int*)d_in[6];
    const float* mask = (const float*)d_in[7];
    int E = in_sizes[5];

    char* ws = (char*)d_ws;
    float* pv      = (float*)(ws + PV_OFF);
    int*   row_off = (int*)  (ws + ROFF_OFF);
    float* G       = (float*)(ws + G_OFF);

    prep_kernel<<<(N_NODES + 256) / 256, 256, 0, stream>>>(pos0, vel, dst, mask, E, row_off, pv);
    scatter_kernel<<<N_NODES / 4, 256, 0, stream>>>(pv, pos1, src, row_off, G);
    gemm_kernel<<<N_NODES / 8, 256, 0, stream>>>(G, W, b, (float*)d_out);
}

// Round 4
// 68.430 us; speedup vs baseline: 4.9420x; 1.0120x over previous
//
#include <hip/hip_runtime.h>
#include <math.h>

// Problem constants (from reference)
#define N_NODES 8192        // N_IN == N_OUT == 8192
#define C_OUT 32
#define GDIM  192           // 64 cells * 3 input channels
constexpr float INV_RADIUS   = 1.0f / 0.1125f;   // RADIUS = 1.5*6*0.025/2
constexpr float EPS          = 1e-12f;
constexpr float FOUR_OVER_PI = 1.27323954473516f;

__device__ __forceinline__ float sgnf(float v) {
    return (v > 0.f) ? 1.f : ((v < 0.f) ? -1.f : 0.f);
}

// Workspace layout (d_ws):
//   pv      : 8192 * 8 floats  (pos.xyz,0, vel.xyz,0)   = 262144 B  @ 0
//   row_off : 8193 ints                                  =  32772 B  @ 262144
//   G       : 8192 * 192 floats                          = 6291456 B @ 294928 (16B aligned)
#define PV_OFF   0
#define ROFF_OFF 262144
#define G_OFF    294928

// Kernel 1: CSR row offsets from sorted dst + pack pos0/vel into float4 pairs.
__global__ __launch_bounds__(256) void prep_kernel(
    const float* __restrict__ pos0,
    const float* __restrict__ vel,
    const int*   __restrict__ dst,
    const float* __restrict__ mask,
    int E,
    int*   __restrict__ row_off,
    float* __restrict__ pv)
{
    int n = blockIdx.x * blockDim.x + threadIdx.x;
    if (n < N_NODES) {
        float4 p = make_float4(pos0[3*n+0], pos0[3*n+1], pos0[3*n+2], 0.f);
        float4 v = make_float4(vel [3*n+0], vel [3*n+1], vel [3*n+2], 0.f);
        ((float4*)pv)[2*n+0] = p;
        ((float4*)pv)[2*n+1] = v;
    }
    if (n > N_NODES) return;
    // E_real = first index where mask == 0
    int lo = 0, hi = E;
    while (lo < hi) { int mid = (lo + hi) >> 1; if (mask[mid] != 0.f) lo = mid + 1; else hi = mid; }
    int Ereal = lo;
    if (n == N_NODES) { row_off[n] = Ereal; return; }
    // lower_bound(dst[0:Ereal], n)
    lo = 0; hi = Ereal;
    while (lo < hi) { int mid = (lo + hi) >> 1; if (dst[mid] < n) lo = mid + 1; else hi = mid; }
    row_off[n] = lo;
}

// Kernel 2: one wave per destination node; accumulate density row in LDS
// via TRUE ds_add_f32 (workgroup-scope relaxed atomic on direct shared lvalue).
__global__ __launch_bounds__(256) void scatter_kernel(
    const float* __restrict__ pv,
    const float* __restrict__ pos1,
    const int*   __restrict__ src,
    const int*   __restrict__ row_off,
    float* __restrict__ G)
{
    __shared__ float Gl[4][GDIM];                   // 3 KiB
    int t = threadIdx.x, wave = t >> 6, lane = t & 63;
    int n = blockIdx.x * 4 + wave;

    // zero own row (wave-private; LDS ops are in-order per wave: no barrier)
    #pragma unroll
    for (int i = lane; i < GDIM; i += 64) Gl[wave][i] = 0.f;

    float px = pos1[3*n+0], py = pos1[3*n+1], pz = pos1[3*n+2];
    int e0 = row_off[n], e1 = row_off[n+1];

    for (int e = e0 + lane; e < e1; e += 64) {
        int s = src[e];
        float4 p = ((const float4*)pv)[2*s+0];
        float4 v = ((const float4*)pv)[2*s+1];
        float rx = (p.x - px) * INV_RADIUS;
        float ry = (p.y - py) * INV_RADIUS;
        float rz = (p.z - pz) * INV_RADIUS;
        float r2 = rx*rx + ry*ry + rz*rz;
        if (r2 >= 1.f) continue;
        float om  = 1.f - r2;
        float win = om*om*om;                       // mask==1 for all real edges

        // ball -> cube (volume preserving)
        float x = rx, y = ry, z = rz;
        float norm = sqrtf(r2 + EPS);
        float cx, cy, cz;
        if (r2 < 1e-12f) {
            cx = 0.f; cy = 0.f; cz = 0.f;
        } else if (1.25f*z*z > x*x + y*y) {         // top/bottom cone
            float s_top = sqrtf(3.f*norm / (norm + fabsf(z) + EPS));
            cx = x * s_top;
            cy = y * s_top;
            cz = sgnf(z) * norm;
        } else {                                    // side
            float s_side = norm * rsqrtf(x*x + y*y + EPS);
            cx = x * s_side;
            cy = y * s_side;
            cz = 1.5f * z;
        }

        float nxy = sqrtf(cx*cx + cy*cy + EPS);
        float ux, uy;
        if (cx*cx >= cy*cy) {
            float xs = (fabsf(cx) > EPS) ? cx : 1.f;
            float sc = sgnf(cx);
            ux = sc * nxy;
            uy = sc * nxy * FOUR_OVER_PI * atanf(cy / xs);
        } else {
            float ys = (fabsf(cy) > EPS) ? cy : 1.f;
            float sc = sgnf(cy);
            ux = sc * nxy * FOUR_OVER_PI * atanf(cx / ys);
            uy = sc * nxy;
        }
        if (cx*cx + cy*cy < 1e-12f) { ux = 0.f; uy = 0.f; }

        // grid coords in [0,3], corner index + fractions
        float gx = fminf(fmaxf((ux + 1.f) * 1.5f, 0.f), 3.f);
        float gy = fminf(fmaxf((uy + 1.f) * 1.5f, 0.f), 3.f);
        float gz = fminf(fmaxf((cz + 1.f) * 1.5f, 0.f), 3.f);
        int ix = min((int)floorf(gx), 2);
        int iy = min((int)floorf(gy), 2);
        int iz = min((int)floorf(gz), 2);
        float fx = gx - (float)ix;
        float fy = gy - (float)iy;
        float fz = gz - (float)iz;

        float ofx = 1.f - fx, ofy = 1.f - fy, ofz = 1.f - fz;
        int base = (iz * 4 + iy) * 4 + ix;          // corner (dz,dy,dx) adds (16dz+4dy+dx)

        // Visit the 8 corners in a lane-rotated order: lanes whose edges share a
        // base cell hit DIFFERENT corner addresses on each DS instruction,
        // eliminating same-address atomic serialization.
        int rot = lane & 7;
        #pragma unroll
        for (int k = 0; k < 8; ++k) {
            int c  = k ^ rot;                       // bijection over 0..7
            float wz = (c & 4) ? fz : ofz;
            float wy = (c & 2) ? fy : ofy;
            float wx = (c & 1) ? fx : ofx;
            float w  = wz * wy * wx * win;
            int idx  = base + ((c & 4) << 2) + ((c & 2) << 1) + (c & 1); // +16dz+4dy+dx
            int a    = idx * 3;
            __hip_atomic_fetch_add(&Gl[wave][a + 0], w * v.x,
                                   __ATOMIC_RELAXED, __HIP_MEMORY_SCOPE_WORKGROUP);
            __hip_atomic_fetch_add(&Gl[wave][a + 1], w * v.y,
                                   __ATOMIC_RELAXED, __HIP_MEMORY_SCOPE_WORKGROUP);
            __hip_atomic_fetch_add(&Gl[wave][a + 2], w * v.z,
                                   __ATOMIC_RELAXED, __HIP_MEMORY_SCOPE_WORKGROUP);
        }
    }

    // same-wave DS ordering guarantees visibility; coalesced row store
    if (lane < GDIM/4) {
        float4 r = ((float4*)Gl[wave])[lane];
        ((float4*)(G + (size_t)n * GDIM))[lane] = r;
    }
}

// Kernel 3: out[n][o] = b[o] + sum_j G[n][j] * W[j][o]; 8 nodes per 256-thr block.
__global__ __launch_bounds__(256) void gemm_kernel(
    const float* __restrict__ G,
    const float* __restrict__ W,
    const float* __restrict__ b,
    float* __restrict__ out)
{
    __shared__ float Wl[GDIM * C_OUT];   // 24 KiB
    __shared__ float Gls[8 * GDIM];      //  6 KiB
    __shared__ float bl[C_OUT];
    int t = threadIdx.x;
    for (int i = t; i < GDIM * C_OUT / 4; i += 256)
        ((float4*)Wl)[i] = ((const float4*)W)[i];
    if (t < C_OUT) bl[t] = b[t];
    const float4* Gg = (const float4*)(G + (size_t)blockIdx.x * 8 * GDIM);
    for (int i = t; i < 8 * GDIM / 4; i += 256)
        ((float4*)Gls)[i] = Gg[i];
    __syncthreads();

    int node = t >> 5, o = t & 31;
    const float* g = Gls + node * GDIM;
    float acc = bl[o];
    #pragma unroll 8
    for (int j = 0; j < GDIM; ++j)
        acc += g[j] * Wl[j * C_OUT + o];
    out[(blockIdx.x * 8 + node) * C_OUT + o] = acc;
}

extern "C" void kernel_launch(void* const* d_in, const int* in_sizes, int n_in,
                              void* d_out, int out_size, void* d_ws, size_t ws_size,
                              hipStream_t stream)
{
    const float* vel  = (const float*)d_in[0];
    const float* pos0 = (const float*)d_in[1];
    const float* pos1 = (const float*)d_in[2];
    const float* W    = (const float*)d_in[3];
    const float* b    = (const float*)d_in[4];
    const int*   src  = (const int*)d_in[5];
    const int*   dst  = (const int*)d_in[6];
    const float* mask = (const float*)d_in[7];
    int E = in_sizes[5];

    char* ws = (char*)d_ws;
    float* pv      = (float*)(ws + PV_OFF);
    int*   row_off = (int*)  (ws + ROFF_OFF);
    float* G       = (float*)(ws + G_OFF);

    prep_kernel<<<(N_NODES + 256) / 256, 256, 0, stream>>>(pos0, vel, dst, mask, E, row_off, pv);
    scatter_kernel<<<N_NODES / 4, 256, 0, stream>>>(pv, pos1, src, row_off, G);
    gemm_kernel<<<N_NODES / 8, 256, 0, stream>>>(G, W, b, (float*)d_out);
}